// Round 9
// baseline (258.959 us; speedup 1.0000x reference)
//
#include <hip/hip_runtime.h>
#include <hip/hip_bf16.h>

typedef __attribute__((ext_vector_type(4))) float f32x4;
typedef __attribute__((ext_vector_type(8))) __bf16 bf16x8;

__device__ __forceinline__ unsigned short f2bf(float f) {
    union { float f; unsigned u; } x; x.f = f;
    unsigned r = x.u + 0x7fffu + ((x.u >> 16) & 1u);
    return (unsigned short)(r >> 16);
}
__device__ __forceinline__ float bf2f(unsigned short b) {
    union { unsigned u; float f; } x; x.u = ((unsigned)b) << 16;
    return x.f;
}

__device__ __forceinline__ void gload16(const void* g, void* l) {
    __builtin_amdgcn_global_load_lds(
        (const __attribute__((address_space(1))) unsigned int*)g,
        (__attribute__((address_space(3))) unsigned int*)l,
        16, 0, 0);
}

template <int N> __device__ __forceinline__ void vm_wait();
template <> __device__ __forceinline__ void vm_wait<0>() { asm volatile("s_waitcnt vmcnt(0)" ::: "memory"); }
template <> __device__ __forceinline__ void vm_wait<2>() { asm volatile("s_waitcnt vmcnt(2)" ::: "memory"); }
template <> __device__ __forceinline__ void vm_wait<4>() { asm volatile("s_waitcnt vmcnt(4)" ::: "memory"); }

// -------- wg2 = Wq @ w_gate  (1024 rows) --------
__global__ __launch_bounds__(256) void k_wg2(const float* __restrict__ Wq,
                                             const float* __restrict__ wg,
                                             float* __restrict__ wg2) {
    int lane = threadIdx.x & 63;
    int row = blockIdx.x * 4 + (threadIdx.x >> 6);
    const float4* a = reinterpret_cast<const float4*>(Wq + (size_t)row * 1024);
    const float4* x = reinterpret_cast<const float4*>(wg);
    float s = 0.f;
    for (int i = lane; i < 256; i += 64) {
        float4 av = a[i], bv = x[i];
        s += av.x * bv.x + av.y * bv.y + av.z * bv.z + av.w * bv.w;
    }
#pragma unroll
    for (int o = 1; o < 64; o <<= 1) s += __shfl_xor(s, o);
    if (lane == 0) wg2[row] = s;
}

// ======== prep: conv(pa*decay) | conv(hs)+gates | transpose_w — by block range ========
__global__ __launch_bounds__(256) void k_prep(
    const float* __restrict__ hs, const float* __restrict__ pa,
    const float* __restrict__ Wq, const float* __restrict__ Wk,
    const float* __restrict__ Wv, const float* __restrict__ Wm,
    unsigned short* __restrict__ hs_bf, unsigned short* __restrict__ pa_bf,
    unsigned short* __restrict__ WT, float decay,
    const float* __restrict__ wg2, float* __restrict__ gates) {
    __shared__ float tile[32][33];
    __shared__ float red[4];
    unsigned b = blockIdx.x;
    int t = threadIdx.x;
    if (b < 16384u) {  // pa -> bf16 * decay
        int i = b * 256 + t;
        float4 v = reinterpret_cast<const float4*>(pa)[i];
        union { unsigned short u[4]; uint2 q; } o;
        o.u[0] = f2bf(v.x * decay); o.u[1] = f2bf(v.y * decay);
        o.u[2] = f2bf(v.z * decay); o.u[3] = f2bf(v.w * decay);
        reinterpret_cast<uint2*>(pa_bf)[i] = o.q;
    } else if (b < 24576u) {  // hs -> bf16, one row per block; also gates[row]
        unsigned row = b - 16384u;
        int i = row * 256 + t;
        float4 v = reinterpret_cast<const float4*>(hs)[i];
        union { unsigned short u[4]; uint2 q; } o;
        o.u[0] = f2bf(v.x); o.u[1] = f2bf(v.y);
        o.u[2] = f2bf(v.z); o.u[3] = f2bf(v.w);
        reinterpret_cast<uint2*>(hs_bf)[i] = o.q;
        float4 w = reinterpret_cast<const float4*>(wg2)[t];
        float s = v.x * w.x + v.y * w.y + v.z * w.z + v.w * w.w;
#pragma unroll
        for (int o2 = 1; o2 < 64; o2 <<= 1) s += __shfl_xor(s, o2);
        if ((t & 63) == 0) red[t >> 6] = s;
        __syncthreads();
        if (t == 0) {
            float ss = red[0] + red[1] + red[2] + red[3];
            gates[row] = 1.f / (1.f + __expf(-ss));
        }
    } else {  // transpose 4x [1024x1024] f32 -> bf16
        unsigned bb = b - 24576u;
        int z = bb >> 10, rem = bb & 1023;
        int bx = rem & 31, by = rem >> 5;
        const float* src = z == 0 ? Wq : z == 1 ? Wk : z == 2 ? Wv : Wm;
        unsigned short* dst = WT + (size_t)z * 1024 * 1024;
        int lx = t & 31, ly8 = t >> 5;
        int x = bx * 32 + lx;
#pragma unroll
        for (int i = 0; i < 4; i++)
            tile[ly8 + i * 8][lx] = src[(size_t)(by * 32 + ly8 + i * 8) * 1024 + x];
        __syncthreads();
        int tx = by * 32 + lx;
#pragma unroll
        for (int i = 0; i < 4; i++)
            dst[(size_t)(bx * 32 + ly8 + i * 8) * 1024 + tx] = f2bf(tile[lx][ly8 + i * 8]);
    }
}

// ======== post-QKV: transpose v-part of C3 -> v_t [B][1024][2048] ========
__global__ __launch_bounds__(256) void k_post(const unsigned short* __restrict__ C3,
                                              unsigned short* __restrict__ v_t) {
    __shared__ unsigned short tile[32][33];
    unsigned b = blockIdx.x;
    int t = threadIdx.x;
    int bx = b & 31, by = (b >> 5) & 63, bz = b >> 11;
    int lx = t & 31, ly8 = t >> 5;
    int x = bx * 32 + lx;
#pragma unroll
    for (int i = 0; i < 4; i++) {
        int y = by * 32 + ly8 + i * 8;
        tile[ly8 + i * 8][lx] = C3[(size_t)(bz * 2048 + y) * 3072 + 2048 + x];
    }
    __syncthreads();
    int tx = by * 32 + lx;
#pragma unroll
    for (int i = 0; i < 4; i++) {
        int ty = bx * 32 + ly8 + i * 8;
        v_t[(size_t)bz * 1024 * 2048 + (size_t)ty * 2048 + tx] = tile[lx][ly8 + i * 8];
    }
}

// ================= 8-phase 256-row GEMM body: C[M,N] = A[M,K] @ Bt[N,K]^T =============
// BM=256, BK=64, 512 threads (8 waves). BN=256: MP=2 -> 16 MFMA/phase;
// BN=128: MP=1 -> 8 MFMA/phase. B-frags read once per K-tile (first phase),
// A staged 1 tile ahead, B 2 tiles ahead, counted vmcnt at ph4/ph8 only.
// XOR swizzle both-sides. yf: 0 = xT-fastest XCD chunks, 1 = yT-fastest.
// EPI: 0 C=bf16(acc*alpha); 1 C=bf16((Q+gates[row]*acc)*alpha);
//      4 C=f32(acc / rowsum(partials)) with partials via `gates` [B*2048][8];
//      5 C=bf16(exp(acc*alpha)) + partial rowsums into `gates` ([B*2048][8], col=xT).
template <int BN>
struct Geo {
    static constexpr int WN = BN / 64;
    static constexpr int WM = 8 / WN;
    static constexpr int WROWS = 256 / WM;
    static constexpr int MF = WROWS / 16;
    static constexpr int MP = MF / 4;
    static constexpr int ASZ = 256 * 64 * 2;
    static constexpr int BSZ = BN * 64 * 2;
    static constexpr int BUFSZ = ASZ + BSZ;
};

#define GPH(BUFOFF, MB, LB, STG, VMW)                                                   \
    {                                                                                   \
        const char* aB = smem + (BUFOFF);                                               \
        const char* bB = aB + G::ASZ;                                                   \
        bf16x8 af[G::MP * 2];                                                           \
        _Pragma("unroll") for (int mm = 0; mm < G::MP; ++mm)                            \
        _Pragma("unroll") for (int kk = 0; kk < 2; ++kk) {                              \
            int rowx = wrow + ((MB) + mm) * 16 + fr;                                    \
            int slot = (kk * 4 + kq) ^ (rowx & 7);                                      \
            af[mm * 2 + kk] = *reinterpret_cast<const bf16x8*>(aB + rowx * 128 + slot * 16); \
        }                                                                               \
        if (LB) {                                                                       \
            _Pragma("unroll") for (int nn = 0; nn < 4; ++nn)                            \
            _Pragma("unroll") for (int kk = 0; kk < 2; ++kk) {                          \
                int rowx = wcol + nn * 16 + fr;                                         \
                int slot = (kk * 4 + kq) ^ (rowx & 7);                                  \
                bfrag[nn * 2 + kk] = *reinterpret_cast<const bf16x8*>(bB + rowx * 128 + slot * 16); \
            }                                                                           \
        }                                                                               \
        STG;                                                                            \
        __builtin_amdgcn_sched_barrier(0);                                              \
        VMW;                                                                            \
        __builtin_amdgcn_s_barrier();                                                   \
        asm volatile("s_waitcnt lgkmcnt(0)" ::: "memory");                              \
        __builtin_amdgcn_sched_barrier(0);                                              \
        __builtin_amdgcn_s_setprio(1);                                                  \
        _Pragma("unroll") for (int mm = 0; mm < G::MP; ++mm)                            \
        _Pragma("unroll") for (int nn = 0; nn < 4; ++nn)                                \
        _Pragma("unroll") for (int kk = 0; kk < 2; ++kk)                                \
            acc[(MB) + mm][nn] = __builtin_amdgcn_mfma_f32_16x16x32_bf16(               \
                af[mm * 2 + kk], bfrag[nn * 2 + kk], acc[(MB) + mm][nn], 0, 0, 0);      \
        __builtin_amdgcn_s_setprio(0);                                                  \
        __builtin_amdgcn_sched_barrier(0);                                              \
        __builtin_amdgcn_s_barrier();                                                   \
        __builtin_amdgcn_sched_barrier(0);                                              \
    }

template <int EPI, int BN>
__device__ __forceinline__ void gemm_body(
    char* smem,
    const unsigned short* __restrict__ A, int ldA, long long bsA,
    const unsigned short* __restrict__ Bt, int ldB, long long bsB,
    void* __restrict__ Cv, int ldC, long long bsC,
    const unsigned short* __restrict__ Qm, int ldQ,
    const float* __restrict__ gates, float alpha, int K,
    int NX, int NY, int NB, int yf) {
    using G = Geo<BN>;
    const int NT = K >> 6, NI = K >> 7;

    // bijective XCD swizzle (grid is always a multiple of 8)
    unsigned b = blockIdx.x;
    unsigned wg = (b & 7) * (gridDim.x >> 3) + (b >> 3);
    int xT, yT, zB;
    if (yf) {
        yT = wg % NY; unsigned r2 = wg / NY;
        xT = r2 % NX; zB = (int)(r2 / NX) % NB;
    } else {
        xT = wg % NX; unsigned r2 = wg / NX;
        yT = r2 % NY; zB = (int)(r2 / NY) % NB;
    }

    const unsigned short* Ab = A + (size_t)zB * (size_t)bsA;
    const unsigned short* Bb = Bt + (size_t)zB * (size_t)bsB;

    int t = threadIdx.x, lane = t & 63, wave = t >> 6;
    int wc = wave % G::WN, wr = wave / G::WN;
    int fr = lane & 15, kq = lane >> 4;
    int wrow = wr * G::WROWS, wcol = wc * 64;
    int trow = t >> 3, csx = (t & 7) ^ (trow & 7);
    long long rowTile = (long long)yT * 256, colTile = (long long)xT * BN;

    f32x4 acc[G::MF][4];
#pragma unroll
    for (int m = 0; m < G::MF; ++m)
#pragma unroll
        for (int n = 0; n < 4; ++n) acc[m][n] = (f32x4){0.f, 0.f, 0.f, 0.f};
    bf16x8 bfrag[8];

    auto stageA = [&](int buf, int h, int tt) {
        int kt = tt < NT ? tt : NT - 1;
#pragma unroll
        for (int rr = 0; rr < 2; ++rr) {
            const unsigned short* src =
                Ab + (size_t)(rowTile + h * 128 + rr * 64 + trow) * (size_t)ldA + kt * 64 + csx * 8;
            gload16(src, smem + buf * G::BUFSZ + h * 16384 + rr * 8192 + t * 16);
        }
    };
    auto stageB = [&](int buf, int h, int tt) {
        int kt = tt < NT ? tt : NT - 1;
        if (BN == 256) {
#pragma unroll
            for (int rr = 0; rr < 2; ++rr) {
                const unsigned short* src =
                    Bb + (size_t)(colTile + h * 128 + rr * 64 + trow) * (size_t)ldB + kt * 64 + csx * 8;
                gload16(src, smem + buf * G::BUFSZ + G::ASZ + h * 16384 + rr * 8192 + t * 16);
            }
        } else {
            const unsigned short* src =
                Bb + (size_t)(colTile + h * 64 + trow) * (size_t)ldB + kt * 64 + csx * 8;
            gload16(src, smem + buf * G::BUFSZ + G::ASZ + h * 8192 + t * 16);
        }
    };

    // prologue: tile0 full + tile1 B, drain all
    stageA(0, 0, 0); stageA(0, 1, 0);
    stageB(0, 0, 0); stageB(0, 1, 0);
    stageB(1, 0, 1); stageB(1, 1, 1);
    __builtin_amdgcn_sched_barrier(0);
    vm_wait<0>();
    __builtin_amdgcn_s_barrier();
    __builtin_amdgcn_sched_barrier(0);

    constexpr int VMN = (BN == 256) ? 4 : 2;
    for (int i = 0; i < NI; ++i) {
        int t1 = 2 * i + 1, t2 = 2 * i + 2, t3 = 2 * i + 3;
        GPH(0,          0,         1, stageA(1, 0, t1), (void)0);
        GPH(0,          G::MP,     0, stageA(1, 1, t1), (void)0);
        GPH(0,          2 * G::MP, 0, stageB(0, 0, t2), (void)0);
        GPH(0,          3 * G::MP, 0, stageB(0, 1, t2), vm_wait<VMN>());
        GPH(G::BUFSZ,   0,         1, stageA(0, 0, t2), (void)0);
        GPH(G::BUFSZ,   G::MP,     0, stageA(0, 1, t2), (void)0);
        GPH(G::BUFSZ,   2 * G::MP, 0, stageB(1, 0, t3), (void)0);
        GPH(G::BUFSZ,   3 * G::MP, 0, stageB(1, 1, t3), vm_wait<VMN>());
    }
    vm_wait<0>();

    // epilogue
    long long rb0 = rowTile + wrow + kq * 4;
    long long cb0 = colTile + wcol + fr;
    if (EPI == 0) {
        unsigned short* C = (unsigned short*)Cv + (size_t)zB * (size_t)bsC;
#pragma unroll
        for (int m = 0; m < G::MF; ++m)
#pragma unroll
            for (int n = 0; n < 4; ++n)
#pragma unroll
                for (int r = 0; r < 4; ++r)
                    C[(size_t)(rb0 + m * 16 + r) * (size_t)ldC + cb0 + n * 16] =
                        f2bf(acc[m][n][r] * alpha);
    } else if (EPI == 1) {
        unsigned short* C = (unsigned short*)Cv;
#pragma unroll
        for (int m = 0; m < G::MF; ++m)
#pragma unroll
            for (int r = 0; r < 4; ++r) {
                long long row = rb0 + m * 16 + r;
                float g = gates[row];
#pragma unroll
                for (int n = 0; n < 4; ++n) {
                    long long col = cb0 + n * 16;
                    float v = (bf2f(Qm[(size_t)row * (size_t)ldQ + col]) + g * acc[m][n][r]) * alpha;
                    C[(size_t)row * (size_t)ldC + col] = f2bf(v);
                }
            }
    } else if (EPI == 4) {
        // f32 out scaled by 1/rowsum(partials[zB*2048+row][0..7])
        float* C = (float*)Cv + (size_t)zB * (size_t)bsC;
#pragma unroll
        for (int m = 0; m < G::MF; ++m)
#pragma unroll
            for (int r = 0; r < 4; ++r) {
                long long row = rb0 + m * 16 + r;
                const float4* pp = reinterpret_cast<const float4*>(
                    gates + ((size_t)zB * 2048 + row) * 8);
                float4 p0 = pp[0], p1 = pp[1];
                float g = 1.f / (p0.x + p0.y + p0.z + p0.w + p1.x + p1.y + p1.z + p1.w);
#pragma unroll
                for (int n = 0; n < 4; ++n)
                    C[(size_t)row * (size_t)ldC + cb0 + n * 16] = acc[m][n][r] * g;
            }
    } else if (EPI == 5) {
        // E = exp(acc*alpha) -> bf16, plus per-block partial rowsums -> gates (as f32*)
        unsigned short* C = (unsigned short*)Cv + (size_t)zB * (size_t)bsC;
        float* partials = (float*)gates;  // [B*2048][8], col = xT
        float srow[G::MF][4];
#pragma unroll
        for (int m = 0; m < G::MF; ++m)
#pragma unroll
            for (int r = 0; r < 4; ++r) srow[m][r] = 0.f;
#pragma unroll
        for (int m = 0; m < G::MF; ++m)
#pragma unroll
            for (int n = 0; n < 4; ++n)
#pragma unroll
                for (int r = 0; r < 4; ++r) {
                    float e = __expf(acc[m][n][r] * alpha);
                    C[(size_t)(rb0 + m * 16 + r) * (size_t)ldC + cb0 + n * 16] = f2bf(e);
                    srow[m][r] += e;
                }
#pragma unroll
        for (int m = 0; m < G::MF; ++m)
#pragma unroll
            for (int r = 0; r < 4; ++r) {
#pragma unroll
                for (int msk = 1; msk < 16; msk <<= 1)
                    srow[m][r] += __shfl_xor(srow[m][r], msk);
            }
        float* sums = (float*)smem;  // [256][WN]
        if (fr == 0) {
#pragma unroll
            for (int m = 0; m < G::MF; ++m)
#pragma unroll
                for (int r = 0; r < 4; ++r)
                    sums[(wrow + kq * 4 + m * 16 + r) * G::WN + wc] = srow[m][r];
        }
        __syncthreads();
        if (t < 256) {
            float s = 0.f;
#pragma unroll
            for (int j = 0; j < G::WN; ++j) s += sums[t * G::WN + j];
            partials[((size_t)zB * 2048 + (size_t)rowTile + t) * 8 + xT] = s;
        }
    }
}

#define GEMM_ARGS                                                                     \
    const unsigned short *A, int ldA, long long bsA, const unsigned short *Bt,        \
        int ldB, long long bsB, void *Cv, int ldC, long long bsC,                     \
        const unsigned short *Qm, int ldQ, const float *gates, float alpha, int K,    \
        int NX, int NY, int NB, int yf
#define GEMM_PASS A, ldA, bsA, Bt, ldB, bsB, Cv, ldC, bsC, Qm, ldQ, gates, alpha, K, NX, NY, NB, yf

__global__ __launch_bounds__(512, 2) void k_qkv(GEMM_ARGS) {
    extern __shared__ char smem[];
    gemm_body<0, 128>(smem, GEMM_PASS);
}
__global__ __launch_bounds__(512, 2) void k_mv(GEMM_ARGS) {
    extern __shared__ char smem[];
    gemm_body<0, 128>(smem, GEMM_PASS);
}
__global__ __launch_bounds__(512, 2) void k_u(GEMM_ARGS) {
    extern __shared__ char smem[];
    gemm_body<1, 128>(smem, GEMM_PASS);
}
__global__ __launch_bounds__(512, 2) void k_logits(GEMM_ARGS) {
    extern __shared__ char smem[];
    gemm_body<5, 256>(smem, GEMM_PASS);
}
__global__ __launch_bounds__(512, 2) void k_ctx(GEMM_ARGS) {
    extern __shared__ char smem[];
    gemm_body<4, 128>(smem, GEMM_PASS);
}

extern "C" void kernel_launch(void* const* d_in, const int* in_sizes, int n_in,
                              void* d_out, int out_size, void* d_ws, size_t ws_size,
                              hipStream_t stream) {
    const float* hs = (const float*)d_in[0];
    const float* pa = (const float*)d_in[1];
    const float* Wq = (const float*)d_in[2];
    const float* Wk = (const float*)d_in[3];
    const float* Wv = (const float*)d_in[4];
    const float* Wm = (const float*)d_in[5];
    const float* wg = (const float*)d_in[6];
    float* out = (float*)d_out;

    const int B = 4, S = 2048, H = 1024;
    const size_t BS = (size_t)B * S;
    const size_t BSH = BS * H;
    const size_t BSS = (size_t)B * S * S;
    const float inv_sqrt_h = 0.03125f;
    const float decay = 0.60653065971263342f;  // exp(-0.5)

    char* ws = (char*)d_ws;
    size_t off = 0;
    auto take = [&](size_t bytes) {
        char* p = ws + off;
        off += (bytes + 255) & ~(size_t)255;
        return p;
    };
    unsigned short* hs_bf = (unsigned short*)take(BSH * 2);           // reused as u_bf
    unsigned short* WT    = (unsigned short*)take(4ull * H * H * 2);  // [Wq^T;Wk^T;Wv^T;Wm^T]
    float* wg2            = (float*)take(H * 4);
    float* gates          = (float*)take(BS * 4);
    unsigned short* C3    = (unsigned short*)take(BS * 3 * H * 2);    // q|k|v [8192][3072]
    unsigned short* v_t   = (unsigned short*)take(BSH * 2);           // [B][1024][2048]
    unsigned short* pa_bf = (unsigned short*)take(BSS * 2);           // reused as E (exp logits)
    float* partials       = (float*)take(BS * 8 * 4);                 // [8192][8]
    unsigned short* mv    = (unsigned short*)d_out;  // scratch: dead before final write
    unsigned short* u_bf  = hs_bf;
    unsigned short* probs = pa_bf;  // E values
    unsigned short* WmT   = WT + 3ull * H * H;

    (void)hipFuncSetAttribute((const void*)k_qkv,    hipFuncAttributeMaxDynamicSharedMemorySize, 98304);
    (void)hipFuncSetAttribute((const void*)k_mv,     hipFuncAttributeMaxDynamicSharedMemorySize, 98304);
    (void)hipFuncSetAttribute((const void*)k_u,      hipFuncAttributeMaxDynamicSharedMemorySize, 98304);
    (void)hipFuncSetAttribute((const void*)k_ctx,    hipFuncAttributeMaxDynamicSharedMemorySize, 98304);
    (void)hipFuncSetAttribute((const void*)k_logits, hipFuncAttributeMaxDynamicSharedMemorySize, 131072);

    // 0) wg2 = Wq @ w_gate
    k_wg2<<<dim3(256), 256, 0, stream>>>(Wq, wg, wg2);
    // 1) prep: pa->bf16*decay, hs->bf16 (+gates = sigmoid(hs.wg2)), W transposes
    k_prep<<<dim3(28672), 256, 0, stream>>>(hs, pa, Wq, Wk, Wv, Wm, hs_bf, pa_bf, WT, decay, wg2, gates);
    // 2) QKV merged: C3 = hs_bf @ [Wq|Wk|Wv]  (grid 24x32=768, yf=1: B-panels L2-pinned)
    k_qkv<<<768, 512, 98304, stream>>>(
        hs_bf, H, 0, WT, H, 0, C3, 3 * H, 0, nullptr, 0, nullptr, 1.f, H, 24, 32, 1, 1);
    // 3) post: v^T
    k_post<<<dim3(8192), 256, 0, stream>>>(C3, v_t);
    // 4) mv = (pa*decay) @ v  [batched]  (grid 8x8x4=256)
    k_mv<<<256, 512, 98304, stream>>>(
        pa_bf, S, (long long)S * S, v_t, S, (long long)H * S, mv, H, (long long)S * H,
        nullptr, 0, nullptr, 1.f, S, 8, 8, 4, 1);
    // 5) u = (q + gates * (mv @ Wm)) * inv_sqrt_h  (grid 8x32=256)
    k_u<<<256, 512, 98304, stream>>>(
        mv, H, 0, WmT, H, 0, u_bf, H, 0, C3, 3 * H, gates, inv_sqrt_h, H, 8, 32, 1, 1);
    // 6) E = exp(u @ k^T) [batched] -> bf16 + partial rowsums (no max-sub: logits ~N(0,1))
    k_logits<<<256, 512, 131072, stream>>>(
        u_bf, H, (long long)S * H, C3 + H, 3 * H, (long long)S * 3 * H,
        probs, S, (long long)S * S, nullptr, 0, partials, 1.f, H, 8, 8, 4, 1);
    // 7) context = diag(1/rowsum) * (E @ v)  [batched]  (grid 8x8x4=256) -> f32
    k_ctx<<<256, 512, 98304, stream>>>(
        probs, S, (long long)S * S, v_t, S, (long long)H * S, out, H, (long long)S * H,
        nullptr, 0, partials, 1.f, S, 8, 8, 4, 1);
}

// Round 10
// 230.014 us; speedup vs baseline: 1.1258x; 1.1258x over previous
//
#include <hip/hip_runtime.h>
#include <hip/hip_bf16.h>

typedef __attribute__((ext_vector_type(4))) float f32x4;
typedef __attribute__((ext_vector_type(8))) __bf16 bf16x8;

__device__ __forceinline__ unsigned short f2bf(float f) {
    union { float f; unsigned u; } x; x.f = f;
    unsigned r = x.u + 0x7fffu + ((x.u >> 16) & 1u);
    return (unsigned short)(r >> 16);
}
__device__ __forceinline__ float bf2f(unsigned short b) {
    union { unsigned u; float f; } x; x.u = ((unsigned)b) << 16;
    return x.f;
}

__device__ __forceinline__ void gload16(const void* g, void* l) {
    __builtin_amdgcn_global_load_lds(
        (const __attribute__((address_space(1))) unsigned int*)g,
        (__attribute__((address_space(3))) unsigned int*)l,
        16, 0, 0);
}

template <int N> __device__ __forceinline__ void vm_wait();
template <> __device__ __forceinline__ void vm_wait<0>() { asm volatile("s_waitcnt vmcnt(0)" ::: "memory"); }
template <> __device__ __forceinline__ void vm_wait<2>() { asm volatile("s_waitcnt vmcnt(2)" ::: "memory"); }
template <> __device__ __forceinline__ void vm_wait<4>() { asm volatile("s_waitcnt vmcnt(4)" ::: "memory"); }

// -------- wg2 = Wq @ w_gate  (1024 rows) --------
__global__ __launch_bounds__(256) void k_wg2(const float* __restrict__ Wq,
                                             const float* __restrict__ wg,
                                             float* __restrict__ wg2) {
    int lane = threadIdx.x & 63;
    int row = blockIdx.x * 4 + (threadIdx.x >> 6);
    const float4* a = reinterpret_cast<const float4*>(Wq + (size_t)row * 1024);
    const float4* x = reinterpret_cast<const float4*>(wg);
    float s = 0.f;
    for (int i = lane; i < 256; i += 64) {
        float4 av = a[i], bv = x[i];
        s += av.x * bv.x + av.y * bv.y + av.z * bv.z + av.w * bv.w;
    }
#pragma unroll
    for (int o = 1; o < 64; o <<= 1) s += __shfl_xor(s, o);
    if (lane == 0) wg2[row] = s;
}

// ======== prep: conv(pa*decay) | conv(hs)+gates | transpose_w — by block range ========
__global__ __launch_bounds__(256) void k_prep(
    const float* __restrict__ hs, const float* __restrict__ pa,
    const float* __restrict__ Wq, const float* __restrict__ Wk,
    const float* __restrict__ Wv, const float* __restrict__ Wm,
    unsigned short* __restrict__ hs_bf, unsigned short* __restrict__ pa_bf,
    unsigned short* __restrict__ WT, float decay,
    const float* __restrict__ wg2, float* __restrict__ gates) {
    __shared__ float tile[32][33];
    __shared__ float red[4];
    unsigned b = blockIdx.x;
    int t = threadIdx.x;
    if (b < 16384u) {  // pa -> bf16 * decay
        int i = b * 256 + t;
        float4 v = reinterpret_cast<const float4*>(pa)[i];
        union { unsigned short u[4]; uint2 q; } o;
        o.u[0] = f2bf(v.x * decay); o.u[1] = f2bf(v.y * decay);
        o.u[2] = f2bf(v.z * decay); o.u[3] = f2bf(v.w * decay);
        reinterpret_cast<uint2*>(pa_bf)[i] = o.q;
    } else if (b < 24576u) {  // hs -> bf16, one row per block; also gates[row]
        unsigned row = b - 16384u;
        int i = row * 256 + t;
        float4 v = reinterpret_cast<const float4*>(hs)[i];
        union { unsigned short u[4]; uint2 q; } o;
        o.u[0] = f2bf(v.x); o.u[1] = f2bf(v.y);
        o.u[2] = f2bf(v.z); o.u[3] = f2bf(v.w);
        reinterpret_cast<uint2*>(hs_bf)[i] = o.q;
        float4 w = reinterpret_cast<const float4*>(wg2)[t];
        float s = v.x * w.x + v.y * w.y + v.z * w.z + v.w * w.w;
#pragma unroll
        for (int o2 = 1; o2 < 64; o2 <<= 1) s += __shfl_xor(s, o2);
        if ((t & 63) == 0) red[t >> 6] = s;
        __syncthreads();
        if (t == 0) {
            float ss = red[0] + red[1] + red[2] + red[3];
            gates[row] = 1.f / (1.f + __expf(-ss));
        }
    } else {  // transpose 4x [1024x1024] f32 -> bf16
        unsigned bb = b - 24576u;
        int z = bb >> 10, rem = bb & 1023;
        int bx = rem & 31, by = rem >> 5;
        const float* src = z == 0 ? Wq : z == 1 ? Wk : z == 2 ? Wv : Wm;
        unsigned short* dst = WT + (size_t)z * 1024 * 1024;
        int lx = t & 31, ly8 = t >> 5;
        int x = bx * 32 + lx;
#pragma unroll
        for (int i = 0; i < 4; i++)
            tile[ly8 + i * 8][lx] = src[(size_t)(by * 32 + ly8 + i * 8) * 1024 + x];
        __syncthreads();
        int tx = by * 32 + lx;
#pragma unroll
        for (int i = 0; i < 4; i++)
            dst[(size_t)(bx * 32 + ly8 + i * 8) * 1024 + tx] = f2bf(tile[lx][ly8 + i * 8]);
    }
}

// ================= 8-phase 256-row GEMM body: C[M,N] = A[M,K] @ Bt[N,K]^T =============
// BM=256, BK=64, 512 threads (8 waves). BN=256: MP=2 -> 16 MFMA/phase;
// BN=128: MP=1 -> 8 MFMA/phase. B-frags read once per K-tile (first phase),
// A staged 1 tile ahead, B 2 tiles ahead, counted vmcnt at ph4/ph8 only.
// XOR swizzle both-sides. yf picks XCD-chunk fast axis: choose so that
// (fast-axis span x panel) + (slow-axis panels) per chunk minimizes re-fetch.
// EPI: 0 C=bf16(acc*alpha); 1 C=bf16((Q+gates[row]*acc)*alpha);
//      4 C=f32(acc / rowsum(partials)); 5 C=bf16(exp(acc*alpha)) + partial rowsums.
template <int BN>
struct Geo {
    static constexpr int WN = BN / 64;
    static constexpr int WM = 8 / WN;
    static constexpr int WROWS = 256 / WM;
    static constexpr int MF = WROWS / 16;
    static constexpr int MP = MF / 4;
    static constexpr int ASZ = 256 * 64 * 2;
    static constexpr int BSZ = BN * 64 * 2;
    static constexpr int BUFSZ = ASZ + BSZ;
};

#define GPH(BUFOFF, MB, LB, STG, VMW)                                                   \
    {                                                                                   \
        const char* aB = smem + (BUFOFF);                                               \
        const char* bB = aB + G::ASZ;                                                   \
        bf16x8 af[G::MP * 2];                                                           \
        _Pragma("unroll") for (int mm = 0; mm < G::MP; ++mm)                            \
        _Pragma("unroll") for (int kk = 0; kk < 2; ++kk) {                              \
            int rowx = wrow + ((MB) + mm) * 16 + fr;                                    \
            int slot = (kk * 4 + kq) ^ (rowx & 7);                                      \
            af[mm * 2 + kk] = *reinterpret_cast<const bf16x8*>(aB + rowx * 128 + slot * 16); \
        }                                                                               \
        if (LB) {                                                                       \
            _Pragma("unroll") for (int nn = 0; nn < 4; ++nn)                            \
            _Pragma("unroll") for (int kk = 0; kk < 2; ++kk) {                          \
                int rowx = wcol + nn * 16 + fr;                                         \
                int slot = (kk * 4 + kq) ^ (rowx & 7);                                  \
                bfrag[nn * 2 + kk] = *reinterpret_cast<const bf16x8*>(bB + rowx * 128 + slot * 16); \
            }                                                                           \
        }                                                                               \
        STG;                                                                            \
        __builtin_amdgcn_sched_barrier(0);                                              \
        VMW;                                                                            \
        __builtin_amdgcn_s_barrier();                                                   \
        asm volatile("s_waitcnt lgkmcnt(0)" ::: "memory");                              \
        __builtin_amdgcn_sched_barrier(0);                                              \
        __builtin_amdgcn_s_setprio(1);                                                  \
        _Pragma("unroll") for (int mm = 0; mm < G::MP; ++mm)                            \
        _Pragma("unroll") for (int nn = 0; nn < 4; ++nn)                                \
        _Pragma("unroll") for (int kk = 0; kk < 2; ++kk)                                \
            acc[(MB) + mm][nn] = __builtin_amdgcn_mfma_f32_16x16x32_bf16(               \
                af[mm * 2 + kk], bfrag[nn * 2 + kk], acc[(MB) + mm][nn], 0, 0, 0);      \
        __builtin_amdgcn_s_setprio(0);                                                  \
        __builtin_amdgcn_sched_barrier(0);                                              \
        __builtin_amdgcn_s_barrier();                                                   \
        __builtin_amdgcn_sched_barrier(0);                                              \
    }

template <int EPI, int BN>
__device__ __forceinline__ void gemm_body(
    char* smem,
    const unsigned short* __restrict__ A, int ldA, long long bsA,
    const unsigned short* __restrict__ Bt, int ldB, long long bsB,
    void* __restrict__ Cv, int ldC, long long bsC,
    const unsigned short* __restrict__ Qm, int ldQ,
    const float* __restrict__ gates, float alpha, int K,
    int NX, int NY, int NB, int yf) {
    using G = Geo<BN>;
    const int NT = K >> 6, NI = K >> 7;

    // bijective XCD swizzle (grid is always a multiple of 8)
    unsigned b = blockIdx.x;
    unsigned wg = (b & 7) * (gridDim.x >> 3) + (b >> 3);
    int xT, yT, zB;
    if (yf) {
        yT = wg % NY; unsigned r2 = wg / NY;
        xT = r2 % NX; zB = (int)(r2 / NX) % NB;
    } else {
        xT = wg % NX; unsigned r2 = wg / NX;
        yT = r2 % NY; zB = (int)(r2 / NY) % NB;
    }

    const unsigned short* Ab = A + (size_t)zB * (size_t)bsA;
    const unsigned short* Bb = Bt + (size_t)zB * (size_t)bsB;

    int t = threadIdx.x, lane = t & 63, wave = t >> 6;
    int wc = wave % G::WN, wr = wave / G::WN;
    int fr = lane & 15, kq = lane >> 4;
    int wrow = wr * G::WROWS, wcol = wc * 64;
    int trow = t >> 3, csx = (t & 7) ^ (trow & 7);
    long long rowTile = (long long)yT * 256, colTile = (long long)xT * BN;

    f32x4 acc[G::MF][4];
#pragma unroll
    for (int m = 0; m < G::MF; ++m)
#pragma unroll
        for (int n = 0; n < 4; ++n) acc[m][n] = (f32x4){0.f, 0.f, 0.f, 0.f};
    bf16x8 bfrag[8];

    auto stageA = [&](int buf, int h, int tt) {
        int kt = tt < NT ? tt : NT - 1;
#pragma unroll
        for (int rr = 0; rr < 2; ++rr) {
            const unsigned short* src =
                Ab + (size_t)(rowTile + h * 128 + rr * 64 + trow) * (size_t)ldA + kt * 64 + csx * 8;
            gload16(src, smem + buf * G::BUFSZ + h * 16384 + rr * 8192 + t * 16);
        }
    };
    auto stageB = [&](int buf, int h, int tt) {
        int kt = tt < NT ? tt : NT - 1;
        if (BN == 256) {
#pragma unroll
            for (int rr = 0; rr < 2; ++rr) {
                const unsigned short* src =
                    Bb + (size_t)(colTile + h * 128 + rr * 64 + trow) * (size_t)ldB + kt * 64 + csx * 8;
                gload16(src, smem + buf * G::BUFSZ + G::ASZ + h * 16384 + rr * 8192 + t * 16);
            }
        } else {
            const unsigned short* src =
                Bb + (size_t)(colTile + h * 64 + trow) * (size_t)ldB + kt * 64 + csx * 8;
            gload16(src, smem + buf * G::BUFSZ + G::ASZ + h * 8192 + t * 16);
        }
    };

    // prologue: tile0 full + tile1 B, drain all
    stageA(0, 0, 0); stageA(0, 1, 0);
    stageB(0, 0, 0); stageB(0, 1, 0);
    stageB(1, 0, 1); stageB(1, 1, 1);
    __builtin_amdgcn_sched_barrier(0);
    vm_wait<0>();
    __builtin_amdgcn_s_barrier();
    __builtin_amdgcn_sched_barrier(0);

    constexpr int VMN = (BN == 256) ? 4 : 2;
    for (int i = 0; i < NI; ++i) {
        int t1 = 2 * i + 1, t2 = 2 * i + 2, t3 = 2 * i + 3;
        GPH(0,          0,         1, stageA(1, 0, t1), (void)0);
        GPH(0,          G::MP,     0, stageA(1, 1, t1), (void)0);
        GPH(0,          2 * G::MP, 0, stageB(0, 0, t2), (void)0);
        GPH(0,          3 * G::MP, 0, stageB(0, 1, t2), vm_wait<VMN>());
        GPH(G::BUFSZ,   0,         1, stageA(0, 0, t2), (void)0);
        GPH(G::BUFSZ,   G::MP,     0, stageA(0, 1, t2), (void)0);
        GPH(G::BUFSZ,   2 * G::MP, 0, stageB(1, 0, t3), (void)0);
        GPH(G::BUFSZ,   3 * G::MP, 0, stageB(1, 1, t3), vm_wait<VMN>());
    }
    vm_wait<0>();

    // epilogue
    long long rb0 = rowTile + wrow + kq * 4;
    long long cb0 = colTile + wcol + fr;
    if (EPI == 0) {
        unsigned short* C = (unsigned short*)Cv + (size_t)zB * (size_t)bsC;
#pragma unroll
        for (int m = 0; m < G::MF; ++m)
#pragma unroll
            for (int n = 0; n < 4; ++n)
#pragma unroll
                for (int r = 0; r < 4; ++r)
                    C[(size_t)(rb0 + m * 16 + r) * (size_t)ldC + cb0 + n * 16] =
                        f2bf(acc[m][n][r] * alpha);
    } else if (EPI == 1) {
        unsigned short* C = (unsigned short*)Cv;
#pragma unroll
        for (int m = 0; m < G::MF; ++m)
#pragma unroll
            for (int r = 0; r < 4; ++r) {
                long long row = rb0 + m * 16 + r;
                float g = gates[row];
#pragma unroll
                for (int n = 0; n < 4; ++n) {
                    long long col = cb0 + n * 16;
                    float v = (bf2f(Qm[(size_t)row * (size_t)ldQ + col]) + g * acc[m][n][r]) * alpha;
                    C[(size_t)row * (size_t)ldC + col] = f2bf(v);
                }
            }
    } else if (EPI == 4) {
        // f32 out scaled by 1/rowsum(partials[zB*2048+row][0..7])
        float* C = (float*)Cv + (size_t)zB * (size_t)bsC;
#pragma unroll
        for (int m = 0; m < G::MF; ++m)
#pragma unroll
            for (int r = 0; r < 4; ++r) {
                long long row = rb0 + m * 16 + r;
                const float4* pp = reinterpret_cast<const float4*>(
                    gates + ((size_t)zB * 2048 + row) * 8);
                float4 p0 = pp[0], p1 = pp[1];
                float g = 1.f / (p0.x + p0.y + p0.z + p0.w + p1.x + p1.y + p1.z + p1.w);
#pragma unroll
                for (int n = 0; n < 4; ++n)
                    C[(size_t)row * (size_t)ldC + cb0 + n * 16] = acc[m][n][r] * g;
            }
    } else if (EPI == 5) {
        // E = exp(acc*alpha) -> bf16, plus per-block partial rowsums -> gates (as f32*)
        unsigned short* C = (unsigned short*)Cv + (size_t)zB * (size_t)bsC;
        float* partials = (float*)gates;  // [B*2048][8], col = xT
        float srow[G::MF][4];
#pragma unroll
        for (int m = 0; m < G::MF; ++m)
#pragma unroll
            for (int r = 0; r < 4; ++r) srow[m][r] = 0.f;
#pragma unroll
        for (int m = 0; m < G::MF; ++m)
#pragma unroll
            for (int n = 0; n < 4; ++n)
#pragma unroll
                for (int r = 0; r < 4; ++r) {
                    float e = __expf(acc[m][n][r] * alpha);
                    C[(size_t)(rb0 + m * 16 + r) * (size_t)ldC + cb0 + n * 16] = f2bf(e);
                    srow[m][r] += e;
                }
#pragma unroll
        for (int m = 0; m < G::MF; ++m)
#pragma unroll
            for (int r = 0; r < 4; ++r) {
#pragma unroll
                for (int msk = 1; msk < 16; msk <<= 1)
                    srow[m][r] += __shfl_xor(srow[m][r], msk);
            }
        float* sums = (float*)smem;  // [256][WN]
        if (fr == 0) {
#pragma unroll
            for (int m = 0; m < G::MF; ++m)
#pragma unroll
                for (int r = 0; r < 4; ++r)
                    sums[(wrow + kq * 4 + m * 16 + r) * G::WN + wc] = srow[m][r];
        }
        __syncthreads();
        if (t < 256) {
            float s = 0.f;
#pragma unroll
            for (int j = 0; j < G::WN; ++j) s += sums[t * G::WN + j];
            partials[((size_t)zB * 2048 + (size_t)rowTile + t) * 8 + xT] = s;
        }
    }
}

#define GEMM_ARGS                                                                     \
    const unsigned short *A, int ldA, long long bsA, const unsigned short *Bt,        \
        int ldB, long long bsB, void *Cv, int ldC, long long bsC,                     \
        const unsigned short *Qm, int ldQ, const float *gates, float alpha, int K,    \
        int NX, int NY, int NB, int yf
#define GEMM_PASS A, ldA, bsA, Bt, ldB, bsB, Cv, ldC, bsC, Qm, ldQ, gates, alpha, K, NX, NY, NB, yf

__global__ __launch_bounds__(512, 2) void k_qk(GEMM_ARGS) {
    extern __shared__ char smem[];
    gemm_body<0, 256>(smem, GEMM_PASS);
}
__global__ __launch_bounds__(512, 2) void k_vt(GEMM_ARGS) {
    extern __shared__ char smem[];
    gemm_body<0, 128>(smem, GEMM_PASS);
}
__global__ __launch_bounds__(512, 2) void k_mv(GEMM_ARGS) {
    extern __shared__ char smem[];
    gemm_body<0, 128>(smem, GEMM_PASS);
}
__global__ __launch_bounds__(512, 2) void k_u(GEMM_ARGS) {
    extern __shared__ char smem[];
    gemm_body<1, 128>(smem, GEMM_PASS);
}
__global__ __launch_bounds__(512, 2) void k_logits(GEMM_ARGS) {
    extern __shared__ char smem[];
    gemm_body<5, 256>(smem, GEMM_PASS);
}
__global__ __launch_bounds__(512, 2) void k_ctx(GEMM_ARGS) {
    extern __shared__ char smem[];
    gemm_body<4, 128>(smem, GEMM_PASS);
}

extern "C" void kernel_launch(void* const* d_in, const int* in_sizes, int n_in,
                              void* d_out, int out_size, void* d_ws, size_t ws_size,
                              hipStream_t stream) {
    const float* hs = (const float*)d_in[0];
    const float* pa = (const float*)d_in[1];
    const float* Wq = (const float*)d_in[2];
    const float* Wk = (const float*)d_in[3];
    const float* Wv = (const float*)d_in[4];
    const float* Wm = (const float*)d_in[5];
    const float* wg = (const float*)d_in[6];
    float* out = (float*)d_out;

    const int B = 4, S = 2048, H = 1024;
    const size_t BS = (size_t)B * S;
    const size_t BSH = BS * H;
    const size_t BSS = (size_t)B * S * S;
    const float inv_sqrt_h = 0.03125f;
    const float decay = 0.60653065971263342f;  // exp(-0.5)

    char* ws = (char*)d_ws;
    size_t off = 0;
    auto take = [&](size_t bytes) {
        char* p = ws + off;
        off += (bytes + 255) & ~(size_t)255;
        return p;
    };
    unsigned short* hs_bf = (unsigned short*)take(BSH * 2);           // reused as u_bf
    unsigned short* WT    = (unsigned short*)take(4ull * H * H * 2);  // [Wq^T;Wk^T;Wv^T;Wm^T]
    float* wg2            = (float*)take(H * 4);
    float* gates          = (float*)take(BS * 4);
    unsigned short* C2    = (unsigned short*)take(BS * 2 * H * 2);    // q|k [8192][2048]
    unsigned short* v_t   = (unsigned short*)take(BSH * 2);           // [B][1024][2048]
    unsigned short* pa_bf = (unsigned short*)take(BSS * 2);           // reused as E (exp logits)
    float* partials       = (float*)take(BS * 8 * 4);                 // [8192][8]
    unsigned short* mv    = (unsigned short*)d_out;  // scratch: dead before final write
    unsigned short* u_bf  = hs_bf;
    unsigned short* probs = pa_bf;  // E values
    unsigned short* WvT   = WT + 2ull * H * H;
    unsigned short* WmT   = WT + 3ull * H * H;

    (void)hipFuncSetAttribute((const void*)k_qk,     hipFuncAttributeMaxDynamicSharedMemorySize, 131072);
    (void)hipFuncSetAttribute((const void*)k_vt,     hipFuncAttributeMaxDynamicSharedMemorySize, 98304);
    (void)hipFuncSetAttribute((const void*)k_mv,     hipFuncAttributeMaxDynamicSharedMemorySize, 98304);
    (void)hipFuncSetAttribute((const void*)k_u,      hipFuncAttributeMaxDynamicSharedMemorySize, 98304);
    (void)hipFuncSetAttribute((const void*)k_ctx,    hipFuncAttributeMaxDynamicSharedMemorySize, 98304);
    (void)hipFuncSetAttribute((const void*)k_logits, hipFuncAttributeMaxDynamicSharedMemorySize, 131072);

    // 0) wg2 = Wq @ w_gate
    k_wg2<<<dim3(256), 256, 0, stream>>>(Wq, wg, wg2);
    // 1) prep: pa->bf16*decay, hs->bf16 (+gates = sigmoid(hs.wg2)), W transposes
    k_prep<<<dim3(28672), 256, 0, stream>>>(hs, pa, Wq, Wk, Wv, Wm, hs_bf, pa_bf, WT, decay, wg2, gates);
    // 2) q|k: C2[8192][2048] = hs_bf @ [Wq|Wk]  (BN=256, grid 8x32=256, yf=0)
    k_qk<<<256, 512, 131072, stream>>>(
        hs_bf, H, 0, WT, H, 0, C2, 2 * H, 0, nullptr, 0, nullptr, 1.f, H, 8, 32, 1, 0);
    // 3) v_t[b] = Wv^T @ hs_b^T  (direct transposed V; grid 16x4x4=256, yf=0)
    k_vt<<<256, 512, 98304, stream>>>(
        WvT, H, 0, hs_bf, H, (long long)S * H, v_t, S, (long long)H * S,
        nullptr, 0, nullptr, 1.f, H, 16, 4, 4, 0);
    // 4) mv = (pa*decay) @ v  [batched]  (grid 8x8x4=256, yf=1)
    k_mv<<<256, 512, 98304, stream>>>(
        pa_bf, S, (long long)S * S, v_t, S, (long long)H * S, mv, H, (long long)S * H,
        nullptr, 0, nullptr, 1.f, S, 8, 8, 4, 1);
    // 5) u = (q + gates * (mv @ Wm)) * inv_sqrt_h  (grid 8x32=256, yf=0)
    k_u<<<256, 512, 98304, stream>>>(
        mv, H, 0, WmT, H, 0, u_bf, H, 0, C2, 2 * H, gates, inv_sqrt_h, H, 8, 32, 1, 0);
    // 6) E = exp(u @ k^T) [batched] -> bf16 + partial rowsums (no max-sub: logits ~N(0,1))
    k_logits<<<256, 512, 131072, stream>>>(
        u_bf, H, (long long)S * H, C2 + H, 2 * H, (long long)S * 2 * H,
        probs, S, (long long)S * S, nullptr, 0, partials, 1.f, H, 8, 8, 4, 1);
    // 7) context = diag(1/rowsum) * (E @ v)  [batched]  (grid 8x8x4=256) -> f32
    k_ctx<<<256, 512, 98304, stream>>>(
        probs, S, (long long)S * S, v_t, S, (long long)H * S, out, H, (long long)S * H,
        nullptr, 0, partials, 1.f, S, 8, 8, 4, 1);
}